// Round 10
// baseline (987.859 us; speedup 1.0000x reference)
//
#include <hip/hip_runtime.h>
#include <hip/hip_fp16.h>
#include <math.h>

// DeeperGCN on MI355X. N=50000, E=625000, D=128, L=7.
// fp16 inter-kernel streams; CSR-by-dst build; degree-sorted (descending)
// node order for aggregation load balance; 16-edge burst gather pipeline
// (comp-then-load rotation -- no slot clobber); direct-exp softmax (logits
// structurally bounded); MFMA GEMM (transposed product, zero LDS) with
// fused bias/res/LN(+ReLU).

constexpr int D = 128;
constexpr int NA = 9;   // atom feats
constexpr int NB = 3;   // bond feats

using half8  = __attribute__((ext_vector_type(8))) _Float16;
using floatx4 = __attribute__((ext_vector_type(4))) float;

// ------------------------- CSR build -------------------------

__global__ void k_hist(const int* __restrict__ dst, int* __restrict__ deg, int E) {
    int e = blockIdx.x * 256 + threadIdx.x;
    if (e < E) atomicAdd(&deg[dst[e]], 1);
}

__global__ void k_scan_a(const int* __restrict__ deg, int* __restrict__ offs,
                         int* __restrict__ bsum, int N) {
    __shared__ int s[256];
    int i = blockIdx.x * 256 + threadIdx.x;
    int v = (i < N) ? deg[i] : 0;
    s[threadIdx.x] = v;
    __syncthreads();
    for (int d = 1; d < 256; d <<= 1) {
        int add = (threadIdx.x >= d) ? s[threadIdx.x - d] : 0;
        __syncthreads();
        s[threadIdx.x] += add;
        __syncthreads();
    }
    if (i < N) offs[i + 1] = s[threadIdx.x];
    if (threadIdx.x == 255) bsum[blockIdx.x] = s[255];
    if (i == 0) offs[0] = 0;
}

// nb must be <= 256 (N=50000 -> nb=196)
__global__ void k_scan_b(const int* __restrict__ bsum, int* __restrict__ bexc, int nb) {
    __shared__ int s[256];
    int t = threadIdx.x;
    int v = (t < nb) ? bsum[t] : 0;
    s[t] = v;
    __syncthreads();
    for (int d = 1; d < 256; d <<= 1) {
        int add = (t >= d) ? s[t - d] : 0;
        __syncthreads();
        s[t] += add;
        __syncthreads();
    }
    if (t < nb) bexc[t] = s[t] - v;  // exclusive block prefix
}

__global__ void k_scan_c(int* __restrict__ offs, const int* __restrict__ bexc, int N) {
    int i = blockIdx.x * 256 + threadIdx.x;
    if (i < N) offs[i + 1] += bexc[blockIdx.x];
}

__global__ void k_fill(const int* __restrict__ src, const int* __restrict__ dst,
                       const int* __restrict__ attr, const int* __restrict__ offs,
                       int* __restrict__ cur, int2* __restrict__ recs, int E) {
    int e = blockIdx.x * 256 + threadIdx.x;
    if (e >= E) return;
    int d = dst[e];
    int pos = offs[d] + atomicAdd(&cur[d], 1);
    int cidx = attr[e * 3] * 64 + attr[e * 3 + 1] * 8 + attr[e * 3 + 2];
    recs[pos] = make_int2(src[e], cidx);
}

// ---------------- degree counting sort (descending) ----------------

__global__ void k_dhist(const int* __restrict__ deg, int* __restrict__ dbin, int N) {
    int i = blockIdx.x * 256 + threadIdx.x;
    if (i >= N) return;
    int d = deg[i]; d = d < 63 ? d : 63;
    atomicAdd(&dbin[63 - d], 1);  // bin 0 = heaviest
}

__global__ void k_dscan(const int* __restrict__ dbin, int* __restrict__ doff) {
    if (threadIdx.x == 0) {
        int acc = 0;
        for (int b = 0; b < 64; ++b) { doff[b] = acc; acc += dbin[b]; }
    }
}

__global__ void k_dfill(const int* __restrict__ deg, const int* __restrict__ doff,
                        int* __restrict__ dcur, int* __restrict__ perm, int N) {
    int i = blockIdx.x * 256 + threadIdx.x;
    if (i >= N) return;
    int d = deg[i]; d = d < 63 ? d : 63;
    int b = 63 - d;
    int pos = doff[b] + atomicAdd(&dcur[b], 1);
    perm[pos] = i;
}

// comb16[c][d] = fp16(b0[c>>6][d] + b1[(c>>3)&7][d] + b2[c&7][d])   (512 x 128)
__global__ void k_comb(const float* __restrict__ bemb, __half* __restrict__ comb16) {
    int gid = blockIdx.x * 256 + threadIdx.x;  // 512*32 float4s
    int c = gid >> 5, q = gid & 31;
    int a0 = c >> 6, a1 = (c >> 3) & 7, a2 = c & 7;
    float4 v0 = *(const float4*)(bemb + (a0)*D + q * 4);
    float4 v1 = *(const float4*)(bemb + (8 + a1) * D + q * 4);
    float4 v2 = *(const float4*)(bemb + (16 + a2) * D + q * 4);
    __half2* c2 = (__half2*)comb16;
    c2[c * 64 + q * 2]     = __floats2half2_rn(v0.x + v1.x + v2.x, v0.y + v1.y + v2.y);
    c2[c * 64 + q * 2 + 1] = __floats2half2_rn(v0.z + v1.z + v2.z, v0.w + v1.w + v2.w);
}

// Wt16[l][f][k] = fp16(W[l][k][f])  -- K-major transposed fp16 weights
__global__ void k_wt(const float* __restrict__ W, __half* __restrict__ Wt16, int total) {
    int o = blockIdx.x * 256 + threadIdx.x;
    if (o >= total) return;
    int l = o >> 14;          // /(128*128)
    int rem = o & 16383;
    int f = rem >> 7, k = rem & 127;
    Wt16[o] = __float2half_rn(W[(l << 14) + k * 128 + f]);
}

// ------------------------- Atom encoder -------------------------

__global__ void k_atom(const int* __restrict__ x, const float* __restrict__ aemb,
                       __half* __restrict__ h16, int N) {
    int wid = (blockIdx.x * blockDim.x + threadIdx.x) >> 6;
    int lane = threadIdx.x & 63;
    if (wid >= N) return;
    const int* xr = x + wid * NA;
    float ax = 0.f, ay = 0.f;
#pragma unroll
    for (int f = 0; f < NA; ++f) {
        int v = xr[f];  // wave-uniform broadcast
        const float2 e = *(const float2*)(aemb + (f * 64 + v) * D + 2 * lane);
        ax += e.x; ay += e.y;
    }
    ((__half2*)h16)[wid * 64 + lane] = __floats2half2_rn(ax, ay);
}

// ------------------------- Aggregation ------------------------------------
// wave per node (degree-sorted order); t16[n] = h16[n] + m[n].
// 16-edge burst gather: prime all 16 loads, steady-state = comp 16 (fully
// live), then burst-load next 16; masked tail. fp32 message math.

__global__ __launch_bounds__(256) void k_agg(const __half* __restrict__ h16,
                      const int2* __restrict__ recs,
                      const int* __restrict__ offs, const __half* __restrict__ comb16,
                      const int* __restrict__ perm,
                      __half* __restrict__ t16, int N) {
    int wid = (blockIdx.x * blockDim.x + threadIdx.x) >> 6;
    int lane = threadIdx.x & 63;
    if (wid >= N) return;
    int nid = perm[wid];  // wave-uniform
    int su = __builtin_amdgcn_readfirstlane(offs[nid]);
    int eu = __builtin_amdgcn_readfirstlane(offs[nid + 1]);
    __half2 hm2 = ((const __half2*)h16)[nid * 64 + lane];
    if (su >= eu) {  // empty segment: m = 0
        ((__half2*)t16)[nid * 64 + lane] = hm2;
        return;
    }
    constexpr float L2E = 1.4426950408889634f;
    float Sx = 0.f, Sy = 0.f, Wx = 0.f, Wy = 0.f;
    int last = eu - 1;

    const __half2* hrow = (const __half2*)h16 + lane;    // row r at hrow[r*64]
    const __half2* crow = (const __half2*)comb16 + lane;

    __half2 hq[16], cq[16];

    auto load4 = [&](int base, int slot) {
#pragma unroll
        for (int i = 0; i < 4; ++i) {
            int idx = base + i; idx = (idx < last) ? idx : last;
            int2 rr = recs[idx];
            int sj = __builtin_amdgcn_readfirstlane(rr.x);
            int cj = __builtin_amdgcn_readfirstlane(rr.y);
            hq[slot * 4 + i] = hrow[sj * 64];
            cq[slot * 4 + i] = crow[cj * 64];
        }
    };
    auto comp4 = [&](int gb, int slot) {
#pragma unroll
        for (int i = 0; i < 4; ++i) {
            float hx = __low2float(hq[slot * 4 + i]), hy = __high2float(hq[slot * 4 + i]);
            float cx = __low2float(cq[slot * 4 + i]), cy = __high2float(cq[slot * 4 + i]);
            float vx = fmaxf(hx + cx, 0.f) + 1e-7f;
            float vy = fmaxf(hy + cy, 0.f) + 1e-7f;
            bool valid = (gb + i) < eu;  // wave-uniform
            float ux = valid ? vx * L2E : -INFINITY;
            float uy = valid ? vy * L2E : -INFINITY;
            float px = __builtin_amdgcn_exp2f(ux);
            float py = __builtin_amdgcn_exp2f(uy);
            Sx += px; Sy += py;
            Wx = fmaf(px, vx, Wx);
            Wy = fmaf(py, vy, Wy);
        }
    };

    // prime: burst-issue up to 16 gathers (only live groups)
    load4(su, 0);
    if (su + 4  < eu) load4(su + 4, 1);
    if (su + 8  < eu) load4(su + 8, 2);
    if (su + 12 < eu) load4(su + 12, 3);

    int e = su;
    for (; e + 16 < eu; e += 16) {  // steady state: all 16 current edges live
        comp4(e, 0); comp4(e + 4, 1); comp4(e + 8, 2); comp4(e + 12, 3);
        load4(e + 16, 0); load4(e + 20, 1); load4(e + 24, 2); load4(e + 28, 3);
    }
    // tail: slots hold edges e..e+15 (clamped); masked compute
    comp4(e, 0);
    if (e + 4  < eu) comp4(e + 4, 1);
    if (e + 8  < eu) comp4(e + 8, 2);
    if (e + 12 < eu) comp4(e + 12, 3);

    float hx = __low2float(hm2), hy = __high2float(hm2);
    float mx = Wx / (Sx + 1e-16f);
    float my = Wy / (Sy + 1e-16f);
    ((__half2*)t16)[nid * 64 + lane] = __floats2half2_rn(hx + mx, hy + my);
}

// ------------------------- MFMA GEMM + fused LN(+ReLU) ---------------------
// D[f][node] = sum_k Wt16[f][k] * A16[node][k] via v_mfma_f32_16x16x32_f16.
// C/D: col(lane&15)=node, row(quad*4+reg)=f -> lane holds one node's feats;
// LN = per-lane sum + shfl_xor(16,32). No LDS, no barriers.
// MODE 0: write hres16 = o (fp16) and h16 = fp16(relu(LN(o))).
// MODE 1: write out = LN(o) fp32.

template <int MODE>
__global__ __launch_bounds__(256) void k_gemm(const __half* __restrict__ A16,
                                              const __half* __restrict__ Wt16,
                                              const float* __restrict__ bl,
                                              const __half* __restrict__ res16,
                                              __half* __restrict__ hres16,
                                              const float* __restrict__ g,
                                              const float* __restrict__ bta,
                                              __half* __restrict__ h16,
                                              float* __restrict__ out,
                                              int N, int useRes) {
    int lane = threadIdx.x & 63;
    int wave = threadIdx.x >> 6;
    int quad = lane >> 4, col = lane & 15;
    int node = blockIdx.x * 64 + wave * 16 + col;
    bool nok = node < N;
    int nc = nok ? node : N - 1;  // clamp (row N-1 is valid data)

    const __half* arow = A16 + (size_t)nc * 128;
    half8 bfrag[4];
#pragma unroll
    for (int ks = 0; ks < 4; ++ks)
        bfrag[ks] = *(const half8*)(arow + ks * 32 + quad * 8);

    floatx4 acc[8];
#pragma unroll
    for (int ft = 0; ft < 8; ++ft) acc[ft] = (floatx4){0.f, 0.f, 0.f, 0.f};

#pragma unroll
    for (int ft = 0; ft < 8; ++ft) {
        const __half* wrow = Wt16 + (size_t)(ft * 16 + col) * 128;  // A-op: m=f
#pragma unroll
        for (int ks = 0; ks < 4; ++ks) {
            half8 afrag = *(const half8*)(wrow + ks * 32 + quad * 8);
            acc[ft] = __builtin_amdgcn_mfma_f32_16x16x32_f16(afrag, bfrag[ks],
                                                             acc[ft], 0, 0, 0);
        }
    }

    float s = 0.f, ss = 0.f;
#pragma unroll
    for (int ft = 0; ft < 8; ++ft) {
        int f0 = ft * 16 + quad * 4;  // 4 consecutive features per lane
        float4 bb = *(const float4*)(bl + f0);
        float o0 = acc[ft][0] + bb.x, o1 = acc[ft][1] + bb.y;
        float o2 = acc[ft][2] + bb.z, o3 = acc[ft][3] + bb.w;
        if (useRes) {
            uint2 rr = *(const uint2*)(res16 + (size_t)nc * 128 + f0);
            __half2 r01 = *(__half2*)&rr.x, r23 = *(__half2*)&rr.y;
            o0 += __low2float(r01); o1 += __high2float(r01);
            o2 += __low2float(r23); o3 += __high2float(r23);
        }
        acc[ft][0] = o0; acc[ft][1] = o1; acc[ft][2] = o2; acc[ft][3] = o3;
        s += (o0 + o1) + (o2 + o3);
        ss += fmaf(o0, o0, o1 * o1) + fmaf(o2, o2, o3 * o3);
        if (MODE == 0 && nok) {
            __half2 h01 = __floats2half2_rn(o0, o1);
            __half2 h23 = __floats2half2_rn(o2, o3);
            uint2 pk = make_uint2(*(unsigned*)&h01, *(unsigned*)&h23);
            *(uint2*)(hres16 + (size_t)node * 128 + f0) = pk;
        }
    }
    s += __shfl_xor(s, 16, 64);  ss += __shfl_xor(ss, 16, 64);
    s += __shfl_xor(s, 32, 64);  ss += __shfl_xor(ss, 32, 64);
    float mu = s * (1.f / 128.f);
    float var = ss * (1.f / 128.f) - mu * mu;
    float rs = rsqrtf(var + 1e-5f);

#pragma unroll
    for (int ft = 0; ft < 8; ++ft) {
        int f0 = ft * 16 + quad * 4;
        float4 gg = *(const float4*)(g + f0);
        float4 bt = *(const float4*)(bta + f0);
        float l0 = (acc[ft][0] - mu) * rs * gg.x + bt.x;
        float l1 = (acc[ft][1] - mu) * rs * gg.y + bt.y;
        float l2 = (acc[ft][2] - mu) * rs * gg.z + bt.z;
        float l3 = (acc[ft][3] - mu) * rs * gg.w + bt.w;
        if (MODE == 0) {
            l0 = fmaxf(l0, 0.f); l1 = fmaxf(l1, 0.f);
            l2 = fmaxf(l2, 0.f); l3 = fmaxf(l3, 0.f);
            if (nok) {
                __half2 h01 = __floats2half2_rn(l0, l1);
                __half2 h23 = __floats2half2_rn(l2, l3);
                uint2 pk = make_uint2(*(unsigned*)&h01, *(unsigned*)&h23);
                *(uint2*)(h16 + (size_t)node * 128 + f0) = pk;
            }
        } else {
            if (nok)
                *(float4*)(out + (size_t)node * 128 + f0) =
                    make_float4(l0, l1, l2, l3);
        }
    }
}

// ------------------------- Launch -------------------------

extern "C" void kernel_launch(void* const* d_in, const int* in_sizes, int n_in,
                              void* d_out, int out_size, void* d_ws, size_t ws_size,
                              hipStream_t stream) {
    const int*   x    = (const int*)d_in[0];
    const int*   ei   = (const int*)d_in[1];
    const int*   attr = (const int*)d_in[2];
    const float* aemb = (const float*)d_in[3];
    const float* bemb = (const float*)d_in[4];
    const float* Wf   = (const float*)d_in[5];
    const float* bf   = (const float*)d_in[6];
    const float* gam  = (const float*)d_in[7];
    const float* bet  = (const float*)d_in[8];
    float* out = (float*)d_out;

    const int N = in_sizes[0] / NA;        // 50000
    const int E = in_sizes[1] / 2;         // 625000
    const int L = in_sizes[5] / (D * D);   // 7

    char* ws = (char*)d_ws;
    size_t o = 0;
    auto carve = [&](size_t bytes) -> void* {
        void* p = (void*)(ws + o);
        o += (bytes + 255) & ~(size_t)255;
        return p;
    };
    __half* hres16 = (__half*)carve((size_t)N * D * 2);  // fp16 residual chain
    __half* h16    = (__half*)carve((size_t)N * D * 2);  // fp16 gather table
    __half* t16    = (__half*)carve((size_t)N * D * 2);  // fp16 agg output
    int2*   recs   = (int2*)carve((size_t)E * 8);
    __half* comb16 = (__half*)carve(512 * D * 2);
    __half* Wt16   = (__half*)carve((size_t)L * D * D * 2);
    int*    deg    = (int*)carve((size_t)N * 4);
    int*    cur    = (int*)carve((size_t)N * 4);
    int*    offs   = (int*)carve((size_t)(N + 1) * 4);
    int*    perm   = (int*)carve((size_t)N * 4);
    int*    dbin   = (int*)carve(256);
    int*    doff   = (int*)carve(256);
    int*    dcur   = (int*)carve(256);
    int*    bsum   = (int*)carve(4096);
    int*    bexc   = (int*)carve(4096);

    const int* src = ei;
    const int* dst = ei + E;

    hipMemsetAsync(deg, 0, (size_t)N * 4, stream);
    hipMemsetAsync(cur, 0, (size_t)N * 4, stream);
    hipMemsetAsync(dbin, 0, 256, stream);
    hipMemsetAsync(dcur, 0, 256, stream);

    int ebl = (E + 255) / 256;
    int nbl = (N + 255) / 256;  // 196 (<=256 required by k_scan_b)
    k_comb<<<64, 256, 0, stream>>>(bemb, comb16);
    int wtot = L * D * D;
    k_wt<<<(wtot + 255) / 256, 256, 0, stream>>>(Wf, Wt16, wtot);
    k_hist<<<ebl, 256, 0, stream>>>(dst, deg, E);
    k_scan_a<<<nbl, 256, 0, stream>>>(deg, offs, bsum, N);
    k_scan_b<<<1, 256, 0, stream>>>(bsum, bexc, nbl);
    k_scan_c<<<nbl, 256, 0, stream>>>(offs, bexc, N);
    k_fill<<<ebl, 256, 0, stream>>>(src, dst, attr, offs, cur, recs, E);
    k_dhist<<<nbl, 256, 0, stream>>>(deg, dbin, N);
    k_dscan<<<1, 64, 0, stream>>>(dbin, doff);
    k_dfill<<<nbl, 256, 0, stream>>>(deg, doff, dcur, perm, N);

    int wbl = (N * 64 + 255) / 256;  // wave per node
    k_atom<<<wbl, 256, 0, stream>>>(x, aemb, h16, N);

    int gbl = (N + 63) / 64;  // 782 blocks, 64 nodes each
    for (int l = 0; l < L; ++l) {
        k_agg<<<wbl, 256, 0, stream>>>(h16, recs, offs, comb16, perm, t16, N);
        if (l == L - 1) {
            k_gemm<1><<<gbl, 256, 0, stream>>>(t16, Wt16 + l * D * D, bf + l * D,
                                               hres16, hres16,
                                               gam + l * D, bet + l * D, h16, out,
                                               N, 1);
        } else {
            k_gemm<0><<<gbl, 256, 0, stream>>>(t16, Wt16 + l * D * D, bf + l * D,
                                               hres16, hres16,
                                               gam + l * D, bet + l * D, h16, out,
                                               N, l > 0 ? 1 : 0);
        }
    }
}

// Round 11
// 684.826 us; speedup vs baseline: 1.4425x; 1.4425x over previous
//
#include <hip/hip_runtime.h>
#include <hip/hip_fp16.h>
#include <math.h>

// DeeperGCN on MI355X. N=50000, E=625000, D=128, L=7.
// fp16 inter-kernel streams; CSR-by-dst build; degree-sorted (descending)
// node order for aggregation load balance (LDS-aggregated counting sort);
// 16-edge burst gather pipeline; direct-exp softmax; MFMA GEMM (transposed
// product, zero LDS) with fused bias/res/LN(+ReLU).

constexpr int D = 128;
constexpr int NA = 9;   // atom feats
constexpr int NB = 3;   // bond feats

using half8  = __attribute__((ext_vector_type(8))) _Float16;
using floatx4 = __attribute__((ext_vector_type(4))) float;

// ------------------------- CSR build -------------------------

__global__ void k_hist(const int* __restrict__ dst, int* __restrict__ deg, int E) {
    int e = blockIdx.x * 256 + threadIdx.x;
    if (e < E) atomicAdd(&deg[dst[e]], 1);
}

__global__ void k_scan_a(const int* __restrict__ deg, int* __restrict__ offs,
                         int* __restrict__ bsum, int N) {
    __shared__ int s[256];
    int i = blockIdx.x * 256 + threadIdx.x;
    int v = (i < N) ? deg[i] : 0;
    s[threadIdx.x] = v;
    __syncthreads();
    for (int d = 1; d < 256; d <<= 1) {
        int add = (threadIdx.x >= d) ? s[threadIdx.x - d] : 0;
        __syncthreads();
        s[threadIdx.x] += add;
        __syncthreads();
    }
    if (i < N) offs[i + 1] = s[threadIdx.x];
    if (threadIdx.x == 255) bsum[blockIdx.x] = s[255];
    if (i == 0) offs[0] = 0;
}

// nb must be <= 256 (N=50000 -> nb=196)
__global__ void k_scan_b(const int* __restrict__ bsum, int* __restrict__ bexc, int nb) {
    __shared__ int s[256];
    int t = threadIdx.x;
    int v = (t < nb) ? bsum[t] : 0;
    s[t] = v;
    __syncthreads();
    for (int d = 1; d < 256; d <<= 1) {
        int add = (t >= d) ? s[t - d] : 0;
        __syncthreads();
        s[t] += add;
        __syncthreads();
    }
    if (t < nb) bexc[t] = s[t] - v;  // exclusive block prefix
}

__global__ void k_scan_c(int* __restrict__ offs, const int* __restrict__ bexc, int N) {
    int i = blockIdx.x * 256 + threadIdx.x;
    if (i < N) offs[i + 1] += bexc[blockIdx.x];
}

__global__ void k_fill(const int* __restrict__ src, const int* __restrict__ dst,
                       const int* __restrict__ attr, const int* __restrict__ offs,
                       int* __restrict__ cur, int2* __restrict__ recs, int E) {
    int e = blockIdx.x * 256 + threadIdx.x;
    if (e >= E) return;
    int d = dst[e];
    int pos = offs[d] + atomicAdd(&cur[d], 1);
    int cidx = attr[e * 3] * 64 + attr[e * 3 + 1] * 8 + attr[e * 3 + 2];
    recs[pos] = make_int2(src[e], cidx);
}

// ---------------- degree counting sort (descending), LDS-aggregated --------

__global__ void k_dhist(const int* __restrict__ deg, int* __restrict__ dbin, int N) {
    __shared__ int lb[64];
    int t = threadIdx.x;
    if (t < 64) lb[t] = 0;
    __syncthreads();
    int i = blockIdx.x * 256 + t;
    if (i < N) {
        int d = deg[i]; d = d < 63 ? d : 63;
        atomicAdd(&lb[63 - d], 1);  // LDS atomic (bin 0 = heaviest)
    }
    __syncthreads();
    if (t < 64 && lb[t] > 0) atomicAdd(&dbin[t], lb[t]);
}

__global__ void k_dscan(const int* __restrict__ dbin, int* __restrict__ doff) {
    if (threadIdx.x == 0) {
        int acc = 0;
        for (int b = 0; b < 64; ++b) { doff[b] = acc; acc += dbin[b]; }
    }
}

__global__ void k_dfill(const int* __restrict__ deg, const int* __restrict__ doff,
                        int* __restrict__ dcur, int* __restrict__ perm, int N) {
    __shared__ int lc[64], lbase[64];
    int t = threadIdx.x;
    if (t < 64) lc[t] = 0;
    __syncthreads();
    int i = blockIdx.x * 256 + t;
    int b = 0, rank = 0;
    if (i < N) {
        int d = deg[i]; d = d < 63 ? d : 63;
        b = 63 - d;
        rank = atomicAdd(&lc[b], 1);  // LDS rank within block
    }
    __syncthreads();
    if (t < 64 && lc[t] > 0) lbase[t] = atomicAdd(&dcur[t], lc[t]);  // reserve
    __syncthreads();
    if (i < N) perm[doff[b] + lbase[b] + rank] = i;
}

// comb16[c][d] = fp16(b0[c>>6][d] + b1[(c>>3)&7][d] + b2[c&7][d])   (512 x 128)
__global__ void k_comb(const float* __restrict__ bemb, __half* __restrict__ comb16) {
    int gid = blockIdx.x * 256 + threadIdx.x;  // 512*32 float4s
    int c = gid >> 5, q = gid & 31;
    int a0 = c >> 6, a1 = (c >> 3) & 7, a2 = c & 7;
    float4 v0 = *(const float4*)(bemb + (a0)*D + q * 4);
    float4 v1 = *(const float4*)(bemb + (8 + a1) * D + q * 4);
    float4 v2 = *(const float4*)(bemb + (16 + a2) * D + q * 4);
    __half2* c2 = (__half2*)comb16;
    c2[c * 64 + q * 2]     = __floats2half2_rn(v0.x + v1.x + v2.x, v0.y + v1.y + v2.y);
    c2[c * 64 + q * 2 + 1] = __floats2half2_rn(v0.z + v1.z + v2.z, v0.w + v1.w + v2.w);
}

// Wt16[l][f][k] = fp16(W[l][k][f])  -- K-major transposed fp16 weights
__global__ void k_wt(const float* __restrict__ W, __half* __restrict__ Wt16, int total) {
    int o = blockIdx.x * 256 + threadIdx.x;
    if (o >= total) return;
    int l = o >> 14;          // /(128*128)
    int rem = o & 16383;
    int f = rem >> 7, k = rem & 127;
    Wt16[o] = __float2half_rn(W[(l << 14) + k * 128 + f]);
}

// ------------------------- Atom encoder -------------------------

__global__ void k_atom(const int* __restrict__ x, const float* __restrict__ aemb,
                       __half* __restrict__ h16, int N) {
    int wid = (blockIdx.x * blockDim.x + threadIdx.x) >> 6;
    int lane = threadIdx.x & 63;
    if (wid >= N) return;
    const int* xr = x + wid * NA;
    float ax = 0.f, ay = 0.f;
#pragma unroll
    for (int f = 0; f < NA; ++f) {
        int v = xr[f];  // wave-uniform broadcast
        const float2 e = *(const float2*)(aemb + (f * 64 + v) * D + 2 * lane);
        ax += e.x; ay += e.y;
    }
    ((__half2*)h16)[wid * 64 + lane] = __floats2half2_rn(ax, ay);
}

// ------------------------- Aggregation ------------------------------------
// wave per node (degree-sorted order); t16[n] = h16[n] + m[n].
// 16-edge burst gather: prime all 16 loads, steady-state = comp 16 (fully
// live), then burst-load next 16; masked tail. fp32 message math.

__global__ __launch_bounds__(256) void k_agg(const __half* __restrict__ h16,
                      const int2* __restrict__ recs,
                      const int* __restrict__ offs, const __half* __restrict__ comb16,
                      const int* __restrict__ perm,
                      __half* __restrict__ t16, int N) {
    int wid = (blockIdx.x * blockDim.x + threadIdx.x) >> 6;
    int lane = threadIdx.x & 63;
    if (wid >= N) return;
    int nid = perm[wid];  // wave-uniform
    int su = __builtin_amdgcn_readfirstlane(offs[nid]);
    int eu = __builtin_amdgcn_readfirstlane(offs[nid + 1]);
    __half2 hm2 = ((const __half2*)h16)[nid * 64 + lane];
    if (su >= eu) {  // empty segment: m = 0
        ((__half2*)t16)[nid * 64 + lane] = hm2;
        return;
    }
    constexpr float L2E = 1.4426950408889634f;
    float Sx = 0.f, Sy = 0.f, Wx = 0.f, Wy = 0.f;
    int last = eu - 1;

    const __half2* hrow = (const __half2*)h16 + lane;    // row r at hrow[r*64]
    const __half2* crow = (const __half2*)comb16 + lane;

    __half2 hq[16], cq[16];

    auto load4 = [&](int base, int slot) {
#pragma unroll
        for (int i = 0; i < 4; ++i) {
            int idx = base + i; idx = (idx < last) ? idx : last;
            int2 rr = recs[idx];
            int sj = __builtin_amdgcn_readfirstlane(rr.x);
            int cj = __builtin_amdgcn_readfirstlane(rr.y);
            hq[slot * 4 + i] = hrow[sj * 64];
            cq[slot * 4 + i] = crow[cj * 64];
        }
    };
    auto comp4 = [&](int gb, int slot) {
#pragma unroll
        for (int i = 0; i < 4; ++i) {
            float hx = __low2float(hq[slot * 4 + i]), hy = __high2float(hq[slot * 4 + i]);
            float cx = __low2float(cq[slot * 4 + i]), cy = __high2float(cq[slot * 4 + i]);
            float vx = fmaxf(hx + cx, 0.f) + 1e-7f;
            float vy = fmaxf(hy + cy, 0.f) + 1e-7f;
            bool valid = (gb + i) < eu;  // wave-uniform
            float ux = valid ? vx * L2E : -INFINITY;
            float uy = valid ? vy * L2E : -INFINITY;
            float px = __builtin_amdgcn_exp2f(ux);
            float py = __builtin_amdgcn_exp2f(uy);
            Sx += px; Sy += py;
            Wx = fmaf(px, vx, Wx);
            Wy = fmaf(py, vy, Wy);
        }
    };

    // prime: burst-issue up to 16 gathers (only live groups)
    load4(su, 0);
    if (su + 4  < eu) load4(su + 4, 1);
    if (su + 8  < eu) load4(su + 8, 2);
    if (su + 12 < eu) load4(su + 12, 3);

    int e = su;
    for (; e + 16 < eu; e += 16) {  // steady state: all 16 current edges live
        comp4(e, 0); comp4(e + 4, 1); comp4(e + 8, 2); comp4(e + 12, 3);
        load4(e + 16, 0); load4(e + 20, 1); load4(e + 24, 2); load4(e + 28, 3);
    }
    // tail: slots hold edges e..e+15 (clamped); masked compute
    comp4(e, 0);
    if (e + 4  < eu) comp4(e + 4, 1);
    if (e + 8  < eu) comp4(e + 8, 2);
    if (e + 12 < eu) comp4(e + 12, 3);

    float hx = __low2float(hm2), hy = __high2float(hm2);
    float mx = Wx / (Sx + 1e-16f);
    float my = Wy / (Sy + 1e-16f);
    ((__half2*)t16)[nid * 64 + lane] = __floats2half2_rn(hx + mx, hy + my);
}

// ------------------------- MFMA GEMM + fused LN(+ReLU) ---------------------
// D[f][node] = sum_k Wt16[f][k] * A16[node][k] via v_mfma_f32_16x16x32_f16.
// C/D: col(lane&15)=node, row(quad*4+reg)=f -> lane holds one node's feats;
// LN = per-lane sum + shfl_xor(16,32). No LDS, no barriers.
// MODE 0: write hres16 = o (fp16) and h16 = fp16(relu(LN(o))).
// MODE 1: write out = LN(o) fp32.

template <int MODE>
__global__ __launch_bounds__(256) void k_gemm(const __half* __restrict__ A16,
                                              const __half* __restrict__ Wt16,
                                              const float* __restrict__ bl,
                                              const __half* __restrict__ res16,
                                              __half* __restrict__ hres16,
                                              const float* __restrict__ g,
                                              const float* __restrict__ bta,
                                              __half* __restrict__ h16,
                                              float* __restrict__ out,
                                              int N, int useRes) {
    int lane = threadIdx.x & 63;
    int wave = threadIdx.x >> 6;
    int quad = lane >> 4, col = lane & 15;
    int node = blockIdx.x * 64 + wave * 16 + col;
    bool nok = node < N;
    int nc = nok ? node : N - 1;  // clamp (row N-1 is valid data)

    const __half* arow = A16 + (size_t)nc * 128;
    half8 bfrag[4];
#pragma unroll
    for (int ks = 0; ks < 4; ++ks)
        bfrag[ks] = *(const half8*)(arow + ks * 32 + quad * 8);

    floatx4 acc[8];
#pragma unroll
    for (int ft = 0; ft < 8; ++ft) acc[ft] = (floatx4){0.f, 0.f, 0.f, 0.f};

#pragma unroll
    for (int ft = 0; ft < 8; ++ft) {
        const __half* wrow = Wt16 + (size_t)(ft * 16 + col) * 128;  // A-op: m=f
#pragma unroll
        for (int ks = 0; ks < 4; ++ks) {
            half8 afrag = *(const half8*)(wrow + ks * 32 + quad * 8);
            acc[ft] = __builtin_amdgcn_mfma_f32_16x16x32_f16(afrag, bfrag[ks],
                                                             acc[ft], 0, 0, 0);
        }
    }

    float s = 0.f, ss = 0.f;
#pragma unroll
    for (int ft = 0; ft < 8; ++ft) {
        int f0 = ft * 16 + quad * 4;  // 4 consecutive features per lane
        float4 bb = *(const float4*)(bl + f0);
        float o0 = acc[ft][0] + bb.x, o1 = acc[ft][1] + bb.y;
        float o2 = acc[ft][2] + bb.z, o3 = acc[ft][3] + bb.w;
        if (useRes) {
            uint2 rr = *(const uint2*)(res16 + (size_t)nc * 128 + f0);
            __half2 r01 = *(__half2*)&rr.x, r23 = *(__half2*)&rr.y;
            o0 += __low2float(r01); o1 += __high2float(r01);
            o2 += __low2float(r23); o3 += __high2float(r23);
        }
        acc[ft][0] = o0; acc[ft][1] = o1; acc[ft][2] = o2; acc[ft][3] = o3;
        s += (o0 + o1) + (o2 + o3);
        ss += fmaf(o0, o0, o1 * o1) + fmaf(o2, o2, o3 * o3);
        if (MODE == 0 && nok) {
            __half2 h01 = __floats2half2_rn(o0, o1);
            __half2 h23 = __floats2half2_rn(o2, o3);
            uint2 pk = make_uint2(*(unsigned*)&h01, *(unsigned*)&h23);
            *(uint2*)(hres16 + (size_t)node * 128 + f0) = pk;
        }
    }
    s += __shfl_xor(s, 16, 64);  ss += __shfl_xor(ss, 16, 64);
    s += __shfl_xor(s, 32, 64);  ss += __shfl_xor(ss, 32, 64);
    float mu = s * (1.f / 128.f);
    float var = ss * (1.f / 128.f) - mu * mu;
    float rs = rsqrtf(var + 1e-5f);

#pragma unroll
    for (int ft = 0; ft < 8; ++ft) {
        int f0 = ft * 16 + quad * 4;
        float4 gg = *(const float4*)(g + f0);
        float4 bt = *(const float4*)(bta + f0);
        float l0 = (acc[ft][0] - mu) * rs * gg.x + bt.x;
        float l1 = (acc[ft][1] - mu) * rs * gg.y + bt.y;
        float l2 = (acc[ft][2] - mu) * rs * gg.z + bt.z;
        float l3 = (acc[ft][3] - mu) * rs * gg.w + bt.w;
        if (MODE == 0) {
            l0 = fmaxf(l0, 0.f); l1 = fmaxf(l1, 0.f);
            l2 = fmaxf(l2, 0.f); l3 = fmaxf(l3, 0.f);
            if (nok) {
                __half2 h01 = __floats2half2_rn(l0, l1);
                __half2 h23 = __floats2half2_rn(l2, l3);
                uint2 pk = make_uint2(*(unsigned*)&h01, *(unsigned*)&h23);
                *(uint2*)(h16 + (size_t)node * 128 + f0) = pk;
            }
        } else {
            if (nok)
                *(float4*)(out + (size_t)node * 128 + f0) =
                    make_float4(l0, l1, l2, l3);
        }
    }
}

// ------------------------- Launch -------------------------

extern "C" void kernel_launch(void* const* d_in, const int* in_sizes, int n_in,
                              void* d_out, int out_size, void* d_ws, size_t ws_size,
                              hipStream_t stream) {
    const int*   x    = (const int*)d_in[0];
    const int*   ei   = (const int*)d_in[1];
    const int*   attr = (const int*)d_in[2];
    const float* aemb = (const float*)d_in[3];
    const float* bemb = (const float*)d_in[4];
    const float* Wf   = (const float*)d_in[5];
    const float* bf   = (const float*)d_in[6];
    const float* gam  = (const float*)d_in[7];
    const float* bet  = (const float*)d_in[8];
    float* out = (float*)d_out;

    const int N = in_sizes[0] / NA;        // 50000
    const int E = in_sizes[1] / 2;         // 625000
    const int L = in_sizes[5] / (D * D);   // 7

    char* ws = (char*)d_ws;
    size_t o = 0;
    auto carve = [&](size_t bytes) -> void* {
        void* p = (void*)(ws + o);
        o += (bytes + 255) & ~(size_t)255;
        return p;
    };
    __half* hres16 = (__half*)carve((size_t)N * D * 2);  // fp16 residual chain
    __half* h16    = (__half*)carve((size_t)N * D * 2);  // fp16 gather table
    __half* t16    = (__half*)carve((size_t)N * D * 2);  // fp16 agg output
    int2*   recs   = (int2*)carve((size_t)E * 8);
    __half* comb16 = (__half*)carve(512 * D * 2);
    __half* Wt16   = (__half*)carve((size_t)L * D * D * 2);
    int*    deg    = (int*)carve((size_t)N * 4);
    int*    cur    = (int*)carve((size_t)N * 4);
    int*    offs   = (int*)carve((size_t)(N + 1) * 4);
    int*    perm   = (int*)carve((size_t)N * 4);
    int*    dbin   = (int*)carve(256);
    int*    doff   = (int*)carve(256);
    int*    dcur   = (int*)carve(256);
    int*    bsum   = (int*)carve(4096);
    int*    bexc   = (int*)carve(4096);

    const int* src = ei;
    const int* dst = ei + E;

    hipMemsetAsync(deg, 0, (size_t)N * 4, stream);
    hipMemsetAsync(cur, 0, (size_t)N * 4, stream);
    hipMemsetAsync(dbin, 0, 256, stream);
    hipMemsetAsync(dcur, 0, 256, stream);

    int ebl = (E + 255) / 256;
    int nbl = (N + 255) / 256;  // 196 (<=256 required by k_scan_b)
    k_comb<<<64, 256, 0, stream>>>(bemb, comb16);
    int wtot = L * D * D;
    k_wt<<<(wtot + 255) / 256, 256, 0, stream>>>(Wf, Wt16, wtot);
    k_hist<<<ebl, 256, 0, stream>>>(dst, deg, E);
    k_scan_a<<<nbl, 256, 0, stream>>>(deg, offs, bsum, N);
    k_scan_b<<<1, 256, 0, stream>>>(bsum, bexc, nbl);
    k_scan_c<<<nbl, 256, 0, stream>>>(offs, bexc, N);
    k_fill<<<ebl, 256, 0, stream>>>(src, dst, attr, offs, cur, recs, E);
    k_dhist<<<nbl, 256, 0, stream>>>(deg, dbin, N);
    k_dscan<<<1, 64, 0, stream>>>(dbin, doff);
    k_dfill<<<nbl, 256, 0, stream>>>(deg, doff, dcur, perm, N);

    int wbl = (N * 64 + 255) / 256;  // wave per node
    k_atom<<<wbl, 256, 0, stream>>>(x, aemb, h16, N);

    int gbl = (N + 63) / 64;  // 782 blocks, 64 nodes each
    for (int l = 0; l < L; ++l) {
        k_agg<<<wbl, 256, 0, stream>>>(h16, recs, offs, comb16, perm, t16, N);
        if (l == L - 1) {
            k_gemm<1><<<gbl, 256, 0, stream>>>(t16, Wt16 + l * D * D, bf + l * D,
                                               hres16, hres16,
                                               gam + l * D, bet + l * D, h16, out,
                                               N, 1);
        } else {
            k_gemm<0><<<gbl, 256, 0, stream>>>(t16, Wt16 + l * D * D, bf + l * D,
                                               hres16, hres16,
                                               gam + l * D, bet + l * D, h16, out,
                                               N, l > 0 ? 1 : 0);
        }
    }
}

// Round 12
// 616.899 us; speedup vs baseline: 1.6013x; 1.1101x over previous
//
#include <hip/hip_runtime.h>
#include <hip/hip_fp16.h>
#include <math.h>

// DeeperGCN on MI355X. N=50000, E=625000, D=128, L=7.
// fp16 inter-kernel streams; gather tables (h16, comb16) PRE-SCALED by
// log2(e) so the aggregation logit is a direct packed-fp16 add/max chain;
// CSR-by-dst build; degree-sorted node order (LDS-aggregated counting sort);
// 16-edge burst gather pipeline with unmasked steady state; MFMA GEMM
// (transposed product, zero LDS) with fused bias/res/LN(+ReLU).

constexpr int D = 128;
constexpr int NA = 9;   // atom feats
constexpr int NB = 3;   // bond feats
constexpr float L2E = 1.4426950408889634f;   // log2(e)
constexpr float INV_L2E = 0.6931471805599453f;

using half8  = __attribute__((ext_vector_type(8))) _Float16;
using h2v    = __attribute__((ext_vector_type(2))) _Float16;
using floatx4 = __attribute__((ext_vector_type(4))) float;

// ------------------------- CSR build -------------------------

__global__ void k_hist(const int* __restrict__ dst, int* __restrict__ deg, int E) {
    int e = blockIdx.x * 256 + threadIdx.x;
    if (e < E) atomicAdd(&deg[dst[e]], 1);
}

__global__ void k_scan_a(const int* __restrict__ deg, int* __restrict__ offs,
                         int* __restrict__ bsum, int N) {
    __shared__ int s[256];
    int i = blockIdx.x * 256 + threadIdx.x;
    int v = (i < N) ? deg[i] : 0;
    s[threadIdx.x] = v;
    __syncthreads();
    for (int d = 1; d < 256; d <<= 1) {
        int add = (threadIdx.x >= d) ? s[threadIdx.x - d] : 0;
        __syncthreads();
        s[threadIdx.x] += add;
        __syncthreads();
    }
    if (i < N) offs[i + 1] = s[threadIdx.x];
    if (threadIdx.x == 255) bsum[blockIdx.x] = s[255];
    if (i == 0) offs[0] = 0;
}

// nb must be <= 256 (N=50000 -> nb=196)
__global__ void k_scan_b(const int* __restrict__ bsum, int* __restrict__ bexc, int nb) {
    __shared__ int s[256];
    int t = threadIdx.x;
    int v = (t < nb) ? bsum[t] : 0;
    s[t] = v;
    __syncthreads();
    for (int d = 1; d < 256; d <<= 1) {
        int add = (t >= d) ? s[t - d] : 0;
        __syncthreads();
        s[t] += add;
        __syncthreads();
    }
    if (t < nb) bexc[t] = s[t] - v;  // exclusive block prefix
}

__global__ void k_scan_c(int* __restrict__ offs, const int* __restrict__ bexc, int N) {
    int i = blockIdx.x * 256 + threadIdx.x;
    if (i < N) offs[i + 1] += bexc[blockIdx.x];
}

__global__ void k_fill(const int* __restrict__ src, const int* __restrict__ dst,
                       const int* __restrict__ attr, const int* __restrict__ offs,
                       int* __restrict__ cur, int2* __restrict__ recs, int E) {
    int e = blockIdx.x * 256 + threadIdx.x;
    if (e >= E) return;
    int d = dst[e];
    int pos = offs[d] + atomicAdd(&cur[d], 1);
    int cidx = attr[e * 3] * 64 + attr[e * 3 + 1] * 8 + attr[e * 3 + 2];
    recs[pos] = make_int2(src[e], cidx);
}

// ---------------- degree counting sort (descending), LDS-aggregated --------

__global__ void k_dhist(const int* __restrict__ deg, int* __restrict__ dbin, int N) {
    __shared__ int lb[64];
    int t = threadIdx.x;
    if (t < 64) lb[t] = 0;
    __syncthreads();
    int i = blockIdx.x * 256 + t;
    if (i < N) {
        int d = deg[i]; d = d < 63 ? d : 63;
        atomicAdd(&lb[63 - d], 1);  // LDS atomic (bin 0 = heaviest)
    }
    __syncthreads();
    if (t < 64 && lb[t] > 0) atomicAdd(&dbin[t], lb[t]);
}

__global__ void k_dscan(const int* __restrict__ dbin, int* __restrict__ doff) {
    if (threadIdx.x == 0) {
        int acc = 0;
        for (int b = 0; b < 64; ++b) { doff[b] = acc; acc += dbin[b]; }
    }
}

__global__ void k_dfill(const int* __restrict__ deg, const int* __restrict__ doff,
                        int* __restrict__ dcur, int* __restrict__ perm, int N) {
    __shared__ int lc[64], lbase[64];
    int t = threadIdx.x;
    if (t < 64) lc[t] = 0;
    __syncthreads();
    int i = blockIdx.x * 256 + t;
    int b = 0, rank = 0;
    if (i < N) {
        int d = deg[i]; d = d < 63 ? d : 63;
        b = 63 - d;
        rank = atomicAdd(&lc[b], 1);  // LDS rank within block
    }
    __syncthreads();
    if (t < 64 && lc[t] > 0) lbase[t] = atomicAdd(&dcur[t], lc[t]);  // reserve
    __syncthreads();
    if (i < N) perm[doff[b] + lbase[b] + rank] = i;
}

// comb16[c][d] = fp16(L2E * (b0[c>>6][d] + b1[(c>>3)&7][d] + b2[c&7][d]))
__global__ void k_comb(const float* __restrict__ bemb, __half* __restrict__ comb16) {
    int gid = blockIdx.x * 256 + threadIdx.x;  // 512*32 float4s
    int c = gid >> 5, q = gid & 31;
    int a0 = c >> 6, a1 = (c >> 3) & 7, a2 = c & 7;
    float4 v0 = *(const float4*)(bemb + (a0)*D + q * 4);
    float4 v1 = *(const float4*)(bemb + (8 + a1) * D + q * 4);
    float4 v2 = *(const float4*)(bemb + (16 + a2) * D + q * 4);
    __half2* c2 = (__half2*)comb16;
    c2[c * 64 + q * 2]     = __floats2half2_rn(L2E * (v0.x + v1.x + v2.x),
                                               L2E * (v0.y + v1.y + v2.y));
    c2[c * 64 + q * 2 + 1] = __floats2half2_rn(L2E * (v0.z + v1.z + v2.z),
                                               L2E * (v0.w + v1.w + v2.w));
}

// Wt16[l][f][k] = fp16(W[l][k][f])  -- K-major transposed fp16 weights
__global__ void k_wt(const float* __restrict__ W, __half* __restrict__ Wt16, int total) {
    int o = blockIdx.x * 256 + threadIdx.x;
    if (o >= total) return;
    int l = o >> 14;          // /(128*128)
    int rem = o & 16383;
    int f = rem >> 7, k = rem & 127;
    Wt16[o] = __float2half_rn(W[(l << 14) + k * 128 + f]);
}

// ------------------------- Atom encoder (scaled h16) -------------------------

__global__ void k_atom(const int* __restrict__ x, const float* __restrict__ aemb,
                       __half* __restrict__ h16, int N) {
    int wid = (blockIdx.x * blockDim.x + threadIdx.x) >> 6;
    int lane = threadIdx.x & 63;
    if (wid >= N) return;
    const int* xr = x + wid * NA;
    float ax = 0.f, ay = 0.f;
#pragma unroll
    for (int f = 0; f < NA; ++f) {
        int v = xr[f];  // wave-uniform broadcast
        const float2 e = *(const float2*)(aemb + (f * 64 + v) * D + 2 * lane);
        ax += e.x; ay += e.y;
    }
    ((__half2*)h16)[wid * 64 + lane] = __floats2half2_rn(ax * L2E, ay * L2E);
}

// ------------------------- Aggregation ------------------------------------
// wave per node (degree-sorted order); t16[n] = (h16s[n] + Ws/S) / L2E.
// Tables pre-scaled by L2E: logit u = max(h'+c',0)+eps' directly in packed
// fp16; p = exp2(u); W accumulates p*u (descaled once at the end).
// 16-edge burst gather; unmasked steady state; masked tail.

__global__ __launch_bounds__(256) void k_agg(const __half* __restrict__ h16,
                      const int2* __restrict__ recs,
                      const int* __restrict__ offs, const __half* __restrict__ comb16,
                      const int* __restrict__ perm,
                      __half* __restrict__ t16, int N) {
    int wid = (blockIdx.x * blockDim.x + threadIdx.x) >> 6;
    int lane = threadIdx.x & 63;
    if (wid >= N) return;
    int nid = perm[wid];  // wave-uniform
    int su = __builtin_amdgcn_readfirstlane(offs[nid]);
    int eu = __builtin_amdgcn_readfirstlane(offs[nid + 1]);
    h2v hm2 = ((const h2v*)h16)[nid * 64 + lane];  // scaled self row
    float hsx = (float)hm2[0], hsy = (float)hm2[1];
    if (su >= eu) {  // empty segment: m = 0; descale
        ((__half2*)t16)[nid * 64 + lane] =
            __floats2half2_rn(hsx * INV_L2E, hsy * INV_L2E);
        return;
    }
    float Sx = 0.f, Sy = 0.f, Wx = 0.f, Wy = 0.f;
    int last = eu - 1;

    const h2v* hrow = (const h2v*)h16 + lane;    // row r at hrow[r*64]
    const h2v* crow = (const h2v*)comb16 + lane;

    const h2v zero2 = (h2v)(_Float16)0;
    const h2v eps2  = {(_Float16)(1e-7f * L2E), (_Float16)(1e-7f * L2E)};

    h2v hq[16], cq[16];

    auto load4 = [&](int base, int slot) {
#pragma unroll
        for (int i = 0; i < 4; ++i) {
            int idx = base + i; idx = (idx < last) ? idx : last;
            int2 rr = recs[idx];
            int sj = __builtin_amdgcn_readfirstlane(rr.x);
            int cj = __builtin_amdgcn_readfirstlane(rr.y);
            hq[slot * 4 + i] = hrow[sj * 64];
            cq[slot * 4 + i] = crow[cj * 64];
        }
    };
    // steady state: all 4 edges live -> no mask
    auto comp4u = [&](int slot) {
#pragma unroll
        for (int i = 0; i < 4; ++i) {
            h2v m = hq[slot * 4 + i] + cq[slot * 4 + i];       // v_pk_add_f16
            m = __builtin_elementwise_max(m, zero2);           // v_pk_max_f16
            m = m + eps2;
            float u0 = (float)m[0], u1 = (float)m[1];
            float px = __builtin_amdgcn_exp2f(u0);
            float py = __builtin_amdgcn_exp2f(u1);
            Sx += px; Sy += py;
            Wx = fmaf(px, u0, Wx);
            Wy = fmaf(py, u1, Wy);
        }
    };
    // tail: mask p (not u -- avoids 0*inf NaN in the W fma)
    auto comp4m = [&](int gb, int slot) {
#pragma unroll
        for (int i = 0; i < 4; ++i) {
            h2v m = hq[slot * 4 + i] + cq[slot * 4 + i];
            m = __builtin_elementwise_max(m, zero2);
            m = m + eps2;
            float u0 = (float)m[0], u1 = (float)m[1];
            bool valid = (gb + i) < eu;  // wave-uniform
            float px = valid ? __builtin_amdgcn_exp2f(u0) : 0.f;
            float py = valid ? __builtin_amdgcn_exp2f(u1) : 0.f;
            Sx += px; Sy += py;
            Wx = fmaf(px, u0, Wx);
            Wy = fmaf(py, u1, Wy);
        }
    };

    // prime: burst-issue up to 16 gathers (only live groups)
    load4(su, 0);
    if (su + 4  < eu) load4(su + 4, 1);
    if (su + 8  < eu) load4(su + 8, 2);
    if (su + 12 < eu) load4(su + 12, 3);

    int e = su;
    for (; e + 16 < eu; e += 16) {  // steady state: all 16 current edges live
        comp4u(0); comp4u(1); comp4u(2); comp4u(3);
        load4(e + 16, 0); load4(e + 20, 1); load4(e + 24, 2); load4(e + 28, 3);
    }
    // tail: slots hold edges e..e+15 (clamped); masked compute
    comp4m(e, 0);
    if (e + 4  < eu) comp4m(e + 4, 1);
    if (e + 8  < eu) comp4m(e + 8, 2);
    if (e + 12 < eu) comp4m(e + 12, 3);

    // t = (h_scaled + W/S) / L2E   (W,S in base-2 scaled domain)
    float tx = (hsx + Wx / (Sx + 1e-16f)) * INV_L2E;
    float ty = (hsy + Wy / (Sy + 1e-16f)) * INV_L2E;
    ((__half2*)t16)[nid * 64 + lane] = __floats2half2_rn(tx, ty);
}

// ------------------------- MFMA GEMM + fused LN(+ReLU) ---------------------
// D[f][node] = sum_k Wt16[f][k] * A16[node][k] via v_mfma_f32_16x16x32_f16.
// C/D: col(lane&15)=node, row(quad*4+reg)=f -> lane holds one node's feats;
// LN = per-lane sum + shfl_xor(16,32). No LDS, no barriers.
// MODE 0: write hres16 = o (fp16, unscaled) and h16 = fp16(L2E*relu(LN(o))).
// MODE 1: write out = LN(o) fp32.

template <int MODE>
__global__ __launch_bounds__(256) void k_gemm(const __half* __restrict__ A16,
                                              const __half* __restrict__ Wt16,
                                              const float* __restrict__ bl,
                                              const __half* __restrict__ res16,
                                              __half* __restrict__ hres16,
                                              const float* __restrict__ g,
                                              const float* __restrict__ bta,
                                              __half* __restrict__ h16,
                                              float* __restrict__ out,
                                              int N, int useRes) {
    int lane = threadIdx.x & 63;
    int wave = threadIdx.x >> 6;
    int quad = lane >> 4, col = lane & 15;
    int node = blockIdx.x * 64 + wave * 16 + col;
    bool nok = node < N;
    int nc = nok ? node : N - 1;  // clamp (row N-1 is valid data)

    const __half* arow = A16 + (size_t)nc * 128;
    half8 bfrag[4];
#pragma unroll
    for (int ks = 0; ks < 4; ++ks)
        bfrag[ks] = *(const half8*)(arow + ks * 32 + quad * 8);

    floatx4 acc[8];
#pragma unroll
    for (int ft = 0; ft < 8; ++ft) acc[ft] = (floatx4){0.f, 0.f, 0.f, 0.f};

#pragma unroll
    for (int ft = 0; ft < 8; ++ft) {
        const __half* wrow = Wt16 + (size_t)(ft * 16 + col) * 128;  // A-op: m=f
#pragma unroll
        for (int ks = 0; ks < 4; ++ks) {
            half8 afrag = *(const half8*)(wrow + ks * 32 + quad * 8);
            acc[ft] = __builtin_amdgcn_mfma_f32_16x16x32_f16(afrag, bfrag[ks],
                                                             acc[ft], 0, 0, 0);
        }
    }

    float s = 0.f, ss = 0.f;
#pragma unroll
    for (int ft = 0; ft < 8; ++ft) {
        int f0 = ft * 16 + quad * 4;  // 4 consecutive features per lane
        float4 bb = *(const float4*)(bl + f0);
        float o0 = acc[ft][0] + bb.x, o1 = acc[ft][1] + bb.y;
        float o2 = acc[ft][2] + bb.z, o3 = acc[ft][3] + bb.w;
        if (useRes) {
            uint2 rr = *(const uint2*)(res16 + (size_t)nc * 128 + f0);
            __half2 r01 = *(__half2*)&rr.x, r23 = *(__half2*)&rr.y;
            o0 += __low2float(r01); o1 += __high2float(r01);
            o2 += __low2float(r23); o3 += __high2float(r23);
        }
        acc[ft][0] = o0; acc[ft][1] = o1; acc[ft][2] = o2; acc[ft][3] = o3;
        s += (o0 + o1) + (o2 + o3);
        ss += fmaf(o0, o0, o1 * o1) + fmaf(o2, o2, o3 * o3);
        if (MODE == 0 && nok) {
            __half2 h01 = __floats2half2_rn(o0, o1);
            __half2 h23 = __floats2half2_rn(o2, o3);
            uint2 pk = make_uint2(*(unsigned*)&h01, *(unsigned*)&h23);
            *(uint2*)(hres16 + (size_t)node * 128 + f0) = pk;
        }
    }
    s += __shfl_xor(s, 16, 64);  ss += __shfl_xor(ss, 16, 64);
    s += __shfl_xor(s, 32, 64);  ss += __shfl_xor(ss, 32, 64);
    float mu = s * (1.f / 128.f);
    float var = ss * (1.f / 128.f) - mu * mu;
    float rs = rsqrtf(var + 1e-5f);

#pragma unroll
    for (int ft = 0; ft < 8; ++ft) {
        int f0 = ft * 16 + quad * 4;
        float4 gg = *(const float4*)(g + f0);
        float4 bt = *(const float4*)(bta + f0);
        float l0 = (acc[ft][0] - mu) * rs * gg.x + bt.x;
        float l1 = (acc[ft][1] - mu) * rs * gg.y + bt.y;
        float l2 = (acc[ft][2] - mu) * rs * gg.z + bt.z;
        float l3 = (acc[ft][3] - mu) * rs * gg.w + bt.w;
        if (MODE == 0) {
            l0 = fmaxf(l0, 0.f); l1 = fmaxf(l1, 0.f);
            l2 = fmaxf(l2, 0.f); l3 = fmaxf(l3, 0.f);
            if (nok) {
                __half2 h01 = __floats2half2_rn(l0 * L2E, l1 * L2E);
                __half2 h23 = __floats2half2_rn(l2 * L2E, l3 * L2E);
                uint2 pk = make_uint2(*(unsigned*)&h01, *(unsigned*)&h23);
                *(uint2*)(h16 + (size_t)node * 128 + f0) = pk;
            }
        } else {
            if (nok)
                *(float4*)(out + (size_t)node * 128 + f0) =
                    make_float4(l0, l1, l2, l3);
        }
    }
}

// ------------------------- Launch -------------------------

extern "C" void kernel_launch(void* const* d_in, const int* in_sizes, int n_in,
                              void* d_out, int out_size, void* d_ws, size_t ws_size,
                              hipStream_t stream) {
    const int*   x    = (const int*)d_in[0];
    const int*   ei   = (const int*)d_in[1];
    const int*   attr = (const int*)d_in[2];
    const float* aemb = (const float*)d_in[3];
    const float* bemb = (const float*)d_in[4];
    const float* Wf   = (const float*)d_in[5];
    const float* bf   = (const float*)d_in[6];
    const float* gam  = (const float*)d_in[7];
    const float* bet  = (const float*)d_in[8];
    float* out = (float*)d_out;

    const int N = in_sizes[0] / NA;        // 50000
    const int E = in_sizes[1] / 2;         // 625000
    const int L = in_sizes[5] / (D * D);   // 7

    char* ws = (char*)d_ws;
    size_t o = 0;
    auto carve = [&](size_t bytes) -> void* {
        void* p = (void*)(ws + o);
        o += (bytes + 255) & ~(size_t)255;
        return p;
    };
    __half* hres16 = (__half*)carve((size_t)N * D * 2);  // fp16 residual chain
    __half* h16    = (__half*)carve((size_t)N * D * 2);  // fp16 gather table (x L2E)
    __half* t16    = (__half*)carve((size_t)N * D * 2);  // fp16 agg output
    int2*   recs   = (int2*)carve((size_t)E * 8);
    __half* comb16 = (__half*)carve(512 * D * 2);
    __half* Wt16   = (__half*)carve((size_t)L * D * D * 2);
    int*    deg    = (int*)carve((size_t)N * 4);
    int*    cur    = (int*)carve((size_t)N * 4);
    int*    offs   = (int*)carve((size_t)(N + 1) * 4);
    int*    perm   = (int*)carve((size_t)N * 4);
    int*    dbin   = (int*)carve(256);
    int*    doff   = (int*)carve(256);
    int*    dcur   = (int*)carve(256);
    int*    bsum   = (int*)carve(4096);
    int*    bexc   = (int*)carve(4096);

    const int* src = ei;
    const int* dst = ei + E;

    hipMemsetAsync(deg, 0, (size_t)N * 4, stream);
    hipMemsetAsync(cur, 0, (size_t)N * 4, stream);
    hipMemsetAsync(dbin, 0, 256, stream);
    hipMemsetAsync(dcur, 0, 256, stream);

    int ebl = (E + 255) / 256;
    int nbl = (N + 255) / 256;  // 196 (<=256 required by k_scan_b)
    k_comb<<<64, 256, 0, stream>>>(bemb, comb16);
    int wtot = L * D * D;
    k_wt<<<(wtot + 255) / 256, 256, 0, stream>>>(Wf, Wt16, wtot);
    k_hist<<<ebl, 256, 0, stream>>>(dst, deg, E);
    k_scan_a<<<nbl, 256, 0, stream>>>(deg, offs, bsum, N);
    k_scan_b<<<1, 256, 0, stream>>>(bsum, bexc, nbl);
    k_scan_c<<<nbl, 256, 0, stream>>>(offs, bexc, N);
    k_fill<<<ebl, 256, 0, stream>>>(src, dst, attr, offs, cur, recs, E);
    k_dhist<<<nbl, 256, 0, stream>>>(deg, dbin, N);
    k_dscan<<<1, 64, 0, stream>>>(dbin, doff);
    k_dfill<<<nbl, 256, 0, stream>>>(deg, doff, dcur, perm, N);

    int wbl = (N * 64 + 255) / 256;  // wave per node
    k_atom<<<wbl, 256, 0, stream>>>(x, aemb, h16, N);

    int gbl = (N + 63) / 64;  // 782 blocks, 64 nodes each
    for (int l = 0; l < L; ++l) {
        k_agg<<<wbl, 256, 0, stream>>>(h16, recs, offs, comb16, perm, t16, N);
        if (l == L - 1) {
            k_gemm<1><<<gbl, 256, 0, stream>>>(t16, Wt16 + l * D * D, bf + l * D,
                                               hres16, hres16,
                                               gam + l * D, bet + l * D, h16, out,
                                               N, 1);
        } else {
            k_gemm<0><<<gbl, 256, 0, stream>>>(t16, Wt16 + l * D * D, bf + l * D,
                                               hres16, hres16,
                                               gam + l * D, bet + l * D, h16, out,
                                               N, l > 0 ? 1 : 0);
        }
    }
}